// Round 1
// baseline (2606.793 us; speedup 1.0000x reference)
//
#include <hip/hip_runtime.h>

#define HH 320
#define WW 320
#define CC 64
#define BB 8
static constexpr float EPS = 1e-5f;

// ---------------- conv 3x3, pad 1, fp32 direct ----------------
// Block: 256 threads. Computes 16x16 pixel tile x 16 output channels.
// Thread: 4 oc x 4 px accumulators.
// NORM_IN: input is raw conv output; apply relu((v-mean)*rstd) per (b,ic) on load.
template<int CIN, bool NORM_IN>
__global__ __launch_bounds__(256) void conv3x3_kernel(
    const float* __restrict__ in,      // [B,CIN,H,W]
    const float2* __restrict__ stats,  // [B*CIN] (mean, rstd) when NORM_IN
    const float* __restrict__ wgt,     // [64, CIN, 3, 3]
    const float* __restrict__ bias,    // [64]
    float* __restrict__ out)           // [B,64,H,W]
{
    constexpr int ICS = 4;
    __shared__ float sIn[ICS][18][18];
    __shared__ float sW[CIN * 9 * 16];   // [(ic*3+ky)*3+kx][16 oc]

    const int tid  = threadIdx.x;
    const int tile = blockIdx.x;            // 0..399
    const int ocb  = blockIdx.y * 16;       // oc base
    const int b    = blockIdx.z;
    const int tx0  = (tile % 20) * 16;
    const int ty0  = (tile / 20) * 16;

    const int ocg = tid >> 6;               // 0..3 (one per wave)
    const int pxt = tid & 63;
    const int r   = pxt >> 2;               // 0..15
    const int c4  = (pxt & 3) * 4;          // 0,4,8,12

    // preload ALL weights for this oc-group once
    for (int e = tid; e < CIN * 9 * 16; e += 256) {
        int ocj  = e & 15;
        int rest = e >> 4;
        int kx   = rest % 3;
        int t2   = rest / 3;
        int ky   = t2 % 3;
        int ic   = t2 / 3;
        sW[e] = wgt[((ocb + ocj) * CIN + ic) * 9 + ky * 3 + kx];
    }

    float acc[4][4];
#pragma unroll
    for (int j = 0; j < 4; ++j) {
        float bv = bias[ocb + ocg * 4 + j];
#pragma unroll
        for (int i = 0; i < 4; ++i) acc[j][i] = bv;
    }

    for (int ic0 = 0; ic0 < CIN; ic0 += ICS) {
        __syncthreads();   // protect sIn reuse (and first-iter sW readiness)
        // stage input tile + halo for ICS channels
        for (int e = tid; e < ICS * 18 * 18; e += 256) {
            int icl = e / 324;
            int rem = e - icl * 324;
            int ly  = rem / 18;
            int lx  = rem - ly * 18;
            int gy  = ty0 + ly - 1;
            int gx  = tx0 + lx - 1;
            int ic  = ic0 + icl;
            float v = 0.f;
            if ((unsigned)gy < HH && (unsigned)gx < WW) {
                v = in[((size_t)(b * CIN + ic) * HH + gy) * WW + gx];
                if (NORM_IN) {
                    float2 ms = stats[b * CIN + ic];
                    v = fmaxf((v - ms.x) * ms.y, 0.f);
                }
            }
            sIn[icl][ly][lx] = v;
        }
        __syncthreads();

#pragma unroll
        for (int icl = 0; icl < ICS; ++icl) {
            const int ic = ic0 + icl;
#pragma unroll
            for (int ky = 0; ky < 3; ++ky) {
                float inv[6];
#pragma unroll
                for (int i = 0; i < 6; ++i) inv[i] = sIn[icl][r + ky][c4 + i];
#pragma unroll
                for (int kx = 0; kx < 3; ++kx) {
                    const float4 wv =
                        *(const float4*)&sW[((ic * 3 + ky) * 3 + kx) * 16 + ocg * 4];
                    const float wj[4] = {wv.x, wv.y, wv.z, wv.w};
#pragma unroll
                    for (int j = 0; j < 4; ++j)
#pragma unroll
                        for (int i = 0; i < 4; ++i)
                            acc[j][i] = fmaf(inv[kx + i], wj[j], acc[j][i]);
                }
            }
        }
    }

#pragma unroll
    for (int j = 0; j < 4; ++j) {
        int oc = ocb + ocg * 4 + j;
        float4 v = make_float4(acc[j][0], acc[j][1], acc[j][2], acc[j][3]);
        *(float4*)&out[((size_t)(b * CC + oc) * HH + (ty0 + r)) * WW + tx0 + c4] = v;
    }
}

// ---------------- per-(b,c) mean/rstd ----------------
__global__ __launch_bounds__(256) void stats_kernel(const float* __restrict__ x,
                                                    float2* __restrict__ stats)
{
    const int bc = blockIdx.x;                      // 0..B*C-1
    const float4* p = (const float4*)(x + (size_t)bc * (HH * WW));
    float s = 0.f, ss = 0.f;
    for (int i = threadIdx.x; i < (HH * WW) / 4; i += 256) {
        float4 v = p[i];
        s  += v.x + v.y + v.z + v.w;
        ss += v.x * v.x + v.y * v.y + v.z * v.z + v.w * v.w;
    }
#pragma unroll
    for (int off = 32; off > 0; off >>= 1) {
        s  += __shfl_down(s, off);
        ss += __shfl_down(ss, off);
    }
    __shared__ float2 wsum[4];
    int wid = threadIdx.x >> 6;
    if ((threadIdx.x & 63) == 0) wsum[wid] = make_float2(s, ss);
    __syncthreads();
    if (threadIdx.x == 0) {
        float S = 0.f, SS = 0.f;
#pragma unroll
        for (int w = 0; w < 4; ++w) { S += wsum[w].x; SS += wsum[w].y; }
        const float n    = (float)(HH * WW);
        float mean = S / n;
        float var  = SS / n - mean * mean;
        stats[bc] = make_float2(mean, rsqrtf(var + EPS));
    }
}

// ---------------- in-place normalize + relu ----------------
__global__ __launch_bounds__(256) void finalize_kernel(float* __restrict__ out,
                                                       const float2* __restrict__ stats)
{
    const int idx = blockIdx.x * 256 + threadIdx.x;       // float4 index
    const int bc  = idx / ((HH * WW) / 4);
    float2 ms = stats[bc];
    float4 v = ((float4*)out)[idx];
    v.x = fmaxf((v.x - ms.x) * ms.y, 0.f);
    v.y = fmaxf((v.y - ms.x) * ms.y, 0.f);
    v.z = fmaxf((v.z - ms.x) * ms.y, 0.f);
    v.w = fmaxf((v.w - ms.x) * ms.y, 0.f);
    ((float4*)out)[idx] = v;
}

extern "C" void kernel_launch(void* const* d_in, const int* in_sizes, int n_in,
                              void* d_out, int out_size, void* d_ws, size_t ws_size,
                              hipStream_t stream)
{
    const float* x  = (const float*)d_in[0];
    const float* w1 = (const float*)d_in[1];
    const float* b1 = (const float*)d_in[2];
    const float* w2 = (const float*)d_in[3];
    const float* b2 = (const float*)d_in[4];
    float* out = (float*)d_out;

    float*  h   = (float*)d_ws;                                   // [8,64,320,320] raw conv1
    float2* st1 = (float2*)((char*)d_ws + (size_t)BB * CC * HH * WW * 4);
    float2* st2 = st1 + BB * CC;

    dim3 cgrid(400, 4, BB);  // 20x20 tiles, 4 oc-groups, 8 batch

    conv3x3_kernel<32, false><<<cgrid, 256, 0, stream>>>(x, nullptr, w1, b1, h);
    stats_kernel<<<BB * CC, 256, 0, stream>>>(h, st1);
    conv3x3_kernel<64, true><<<cgrid, 256, 0, stream>>>(h, st1, w2, b2, out);
    stats_kernel<<<BB * CC, 256, 0, stream>>>(out, st2);
    finalize_kernel<<<(BB * CC * HH * WW / 4) / 256, 256, 0, stream>>>(out, st2);
}

// Round 2
// 408.169 us; speedup vs baseline: 6.3865x; 6.3865x over previous
//
#include <hip/hip_runtime.h>

#define HH 320
#define WW 320
#define BB 8
#define COUT 64
#define TX 64
#define TY 4
static constexpr float EPS = 1e-5f;

typedef __attribute__((ext_vector_type(8))) short bf16x8;
typedef __attribute__((ext_vector_type(4))) float f32x4;

__device__ inline float bf2f(unsigned short u) {
    union { unsigned int i; float f; } v; v.i = ((unsigned int)u) << 16; return v.f;
}
__device__ inline unsigned short f2bf(float f) {
    union { float f; unsigned int i; } v; v.f = f;
    unsigned int r = v.i + 0x7fffu + ((v.i >> 16) & 1u);
    return (unsigned short)(r >> 16);
}

// ---------------- NCHW fp32 -> NHWC bf16 ----------------
__global__ __launch_bounds__(256) void prep_hwc(const float* __restrict__ in,
                                                unsigned short* __restrict__ out)
{
    __shared__ float sT[32][65];
    const int tid = threadIdx.x;
    const int x0  = blockIdx.x * 64;
    const int y   = blockIdx.y;
    const int b   = blockIdx.z;
    // load 32c x 64x tile, coalesced along x
    for (int e = tid; e < 32 * 64; e += 256) {
        int c = e >> 6, x = e & 63;
        sT[c][x] = in[(((size_t)(b * 32 + c) * HH) + y) * WW + x0 + x];
    }
    __syncthreads();
    // store NHWC, coalesced along c
    for (int e = tid; e < 64 * 32; e += 256) {
        int x = e >> 5, c = e & 31;
        out[((((size_t)b * HH + y) * WW) + x0 + x) * 32 + c] = f2bf(sT[c][x]);
    }
}

// ---------------- weights OIHW fp32 -> [ky][kx][oc][ic] bf16 ----------------
__global__ void wprep_kernel(const float* __restrict__ w1, const float* __restrict__ w2,
                             unsigned short* __restrict__ wt1, unsigned short* __restrict__ wt2)
{
    int i = blockIdx.x * 256 + threadIdx.x;
    if (i < 9 * 64 * 32) {                    // wt1[kk][oc][ic], CIN=32
        int ic = i & 31, oc = (i >> 5) & 63, kk = i >> 11;
        wt1[i] = f2bf(w1[(oc * 32 + ic) * 9 + kk]);
    }
    if (i < 9 * 64 * 64) {                    // wt2, CIN=64
        int ic = i & 63, oc = (i >> 6) & 63, kk = i >> 12;
        wt2[i] = f2bf(w2[(oc * 64 + ic) * 9 + kk]);
    }
}

// ---------------- implicit-GEMM conv 3x3 via MFMA ----------------
// Block: 256 thr = 4 waves. Tile: 4 rows(y) x 64 px(x) x 64 oc. Wave w owns row y0+w.
// NORM_IN: apply relu((v-mean)*rstd) per channel while staging A.
// OUT_MODE 0: write raw conv NHWC bf16 + per-block stats partials
//          1: stats partials only
//          2: normalize with stats_out + ReLU, transpose, write NCHW fp32
template<int CIN, int NORM_IN, int OUT_MODE>
__global__ __launch_bounds__(256, 2) void conv_mfma(
    const unsigned short* __restrict__ in_hwc,   // [B][H][W][CIN] bf16
    const float2* __restrict__ stats_in,         // [B*CIN] (NORM_IN)
    const unsigned short* __restrict__ wt,       // [3][3][64][CIN] bf16
    const float* __restrict__ bias,              // [64]
    unsigned short* __restrict__ out_hwc,        // OUT_MODE 0
    float2* __restrict__ partials,               // OUT_MODE 0/1: [3200][64]
    const float2* __restrict__ stats_out,        // OUT_MODE 2
    float* __restrict__ out_nchw)                // OUT_MODE 2
{
    __shared__ __align__(16) char smem[80320];
    unsigned short* sA = (unsigned short*)smem;              // [6][66][40] bf16 = 31680 B
    unsigned short* sW = (unsigned short*)smem + 15840;      // [9][64][40] bf16 = 46080 B
    float2* sRed   = (float2*)(smem + 77760);                // [4][64] = 2048 B
    float2* sStats = (float2*)(smem + 79808);                // [64]    = 512 B

    const int tid = threadIdx.x;
    const int bx = blockIdx.x;            // 0..4
    const int by = blockIdx.y;            // 0..79
    const int b  = blockIdx.z;
    const int x0 = bx * TX;
    const int y0 = by * TY;
    const int w  = tid >> 6;              // wave id = row in tile
    const int l  = tid & 63;
    const int lm = l & 15;
    const int g  = l >> 4;

    if (NORM_IN) {
        if (tid < 64) sStats[tid] = stats_in[b * 64 + tid];
    }

    f32x4 acc[4][4];
#pragma unroll
    for (int fx = 0; fx < 4; ++fx)
#pragma unroll
        for (int fn = 0; fn < 4; ++fn)
            acc[fx][fn] = (f32x4){0.f, 0.f, 0.f, 0.f};

    for (int icc = 0; icc < CIN / 32; ++icc) {
        __syncthreads();
        // stage weights chunk: sW[kk][oc][ic0..31]
        for (int e = tid; e < 9 * 64 * 4; e += 256) {
            int icq = e & 3, oc = (e >> 2) & 63, kk = e >> 8;
            bf16x8 v = *(const bf16x8*)&wt[(size_t)(kk * 64 + oc) * CIN + icc * 32 + icq * 8];
            *(bf16x8*)&sW[(kk * 64 + oc) * 40 + icq * 8] = v;
        }
        // stage input tile + halo: sA[r 0..5][x 0..65][ic 0..31]
        for (int e = tid; e < 6 * 66 * 4; e += 256) {
            int icq = e & 3, x = (e >> 2) % 66, r = (e >> 2) / 66;
            int gy = y0 + r - 1, gx = x0 + x - 1;
            unsigned short res[8];
            if ((unsigned)gy < HH && (unsigned)gx < WW) {
                bf16x8 v = *(const bf16x8*)&in_hwc[((((size_t)b * HH + gy) * WW) + gx) * CIN + icc * 32 + icq * 8];
                if (NORM_IN) {
#pragma unroll
                    for (int j = 0; j < 8; ++j) {
                        float2 ms = sStats[icc * 32 + icq * 8 + j];
                        float f = fmaxf((bf2f(((unsigned short*)&v)[j]) - ms.x) * ms.y, 0.f);
                        res[j] = f2bf(f);
                    }
                } else {
#pragma unroll
                    for (int j = 0; j < 8; ++j) res[j] = ((unsigned short*)&v)[j];
                }
            } else {
#pragma unroll
                for (int j = 0; j < 8; ++j) res[j] = 0;
            }
            *(bf16x8*)&sA[((r * 66 + x) * 40) + icq * 8] = *(bf16x8*)res;
        }
        __syncthreads();

#pragma unroll
        for (int kk = 0; kk < 9; ++kk) {
            const int ky = kk / 3, kx = kk % 3;
            bf16x8 af[4], bfr[4];
#pragma unroll
            for (int fx = 0; fx < 4; ++fx)
                af[fx] = *(const bf16x8*)&sA[(((w + ky) * 66 + fx * 16 + lm + kx) * 40) + g * 8];
#pragma unroll
            for (int fn = 0; fn < 4; ++fn)
                bfr[fn] = *(const bf16x8*)&sW[(kk * 64 + fn * 16 + lm) * 40 + g * 8];
#pragma unroll
            for (int fx = 0; fx < 4; ++fx)
#pragma unroll
                for (int fn = 0; fn < 4; ++fn)
                    acc[fx][fn] = __builtin_amdgcn_mfma_f32_16x16x32_bf16(
                        af[fx], bfr[fn], acc[fx][fn], 0, 0, 0);
        }
    }

    float bia[4];
#pragma unroll
    for (int fn = 0; fn < 4; ++fn) bia[fn] = bias[fn * 16 + lm];

    if (OUT_MODE == 0 || OUT_MODE == 1) {
#pragma unroll
        for (int fn = 0; fn < 4; ++fn) {
            float s = 0.f, ss = 0.f;
#pragma unroll
            for (int fx = 0; fx < 4; ++fx) {
#pragma unroll
                for (int j = 0; j < 4; ++j) {
                    float v = acc[fx][fn][j] + bia[fn];
                    s += v; ss += v * v;
                    if (OUT_MODE == 0) {
                        int x = x0 + fx * 16 + g * 4 + j;
                        out_hwc[((((size_t)b * HH + (y0 + w)) * WW) + x) * COUT + fn * 16 + lm] = f2bf(v);
                    }
                }
            }
            s  += __shfl_xor(s, 16);  s  += __shfl_xor(s, 32);
            ss += __shfl_xor(ss, 16); ss += __shfl_xor(ss, 32);
            if (l < 16) sRed[w * 64 + fn * 16 + l] = make_float2(s, ss);
        }
        __syncthreads();
        if (tid < 64) {
            float S = 0.f, SS = 0.f;
#pragma unroll
            for (int q = 0; q < 4; ++q) {
                float2 p = sRed[q * 64 + tid];
                S += p.x; SS += p.y;
            }
            partials[(((size_t)b * 80 + by) * 5 + bx) * 64 + tid] = make_float2(S, SS);
        }
    } else {
        // OUT_MODE 2: normalize + relu + transpose to NCHW fp32
        __syncthreads();                       // everyone done with sA/sW
        float* sOut = (float*)smem;            // [4][64][65] fp32 = 66560 B
#pragma unroll
        for (int fn = 0; fn < 4; ++fn) {
            float2 ms = stats_out[b * 64 + fn * 16 + lm];
#pragma unroll
            for (int fx = 0; fx < 4; ++fx)
#pragma unroll
                for (int j = 0; j < 4; ++j) {
                    float v = fmaxf((acc[fx][fn][j] + bia[fn] - ms.x) * ms.y, 0.f);
                    sOut[(size_t)(w * 64 + fx * 16 + g * 4 + j) * 65 + fn * 16 + lm] = v;
                }
        }
        __syncthreads();
        for (int e = tid; e < 4096; e += 256) {     // float4 units over [4y][64x][64c]
            int xq = e & 15, yc = e >> 4;
            int y = yc >> 6, c = yc & 63;
            float4 v;
            v.x = sOut[(size_t)(y * 64 + xq * 4 + 0) * 65 + c];
            v.y = sOut[(size_t)(y * 64 + xq * 4 + 1) * 65 + c];
            v.z = sOut[(size_t)(y * 64 + xq * 4 + 2) * 65 + c];
            v.w = sOut[(size_t)(y * 64 + xq * 4 + 3) * 65 + c];
            *(float4*)&out_nchw[(((size_t)(b * 64 + c) * HH) + y0 + y) * WW + x0 + xq * 4] = v;
        }
    }
}

// ---------------- partials -> (mean, rstd) ----------------
__global__ __launch_bounds__(256) void reduce_stats(const float2* __restrict__ partials,
                                                    float2* __restrict__ stats)
{
    const int b  = blockIdx.x;        // 0..7
    const int oc = threadIdx.x & 63;
    const int q  = threadIdx.x >> 6;
    float s = 0.f, ss = 0.f;
    for (int i = q; i < 400; i += 4) {
        float2 p = partials[((size_t)b * 400 + i) * 64 + oc];
        s += p.x; ss += p.y;
    }
    __shared__ float2 red[4][64];
    red[q][oc] = make_float2(s, ss);
    __syncthreads();
    if (threadIdx.x < 64) {
        float S = 0.f, SS = 0.f;
#pragma unroll
        for (int k = 0; k < 4; ++k) { S += red[k][threadIdx.x].x; SS += red[k][threadIdx.x].y; }
        const float n = (float)(HH * WW);
        float mean = S / n;
        float var  = fmaxf(SS / n - mean * mean, 0.f);
        stats[b * 64 + threadIdx.x] = make_float2(mean, rsqrtf(var + EPS));
    }
}

extern "C" void kernel_launch(void* const* d_in, const int* in_sizes, int n_in,
                              void* d_out, int out_size, void* d_ws, size_t ws_size,
                              hipStream_t stream)
{
    const float* x  = (const float*)d_in[0];
    const float* w1 = (const float*)d_in[1];
    const float* b1 = (const float*)d_in[2];
    const float* w2 = (const float*)d_in[3];
    const float* b2 = (const float*)d_in[4];
    float* out = (float*)d_out;

    char* ws = (char*)d_ws;
    size_t off = 0;
    unsigned short* h_hwc = (unsigned short*)(ws + off); off += (size_t)BB * HH * WW * 64 * 2;  // 104.86 MB
    unsigned short* x_hwc = (unsigned short*)(ws + off); off += (size_t)BB * HH * WW * 32 * 2;  // 52.4 MB
    unsigned short* wt1   = (unsigned short*)(ws + off); off += 9 * 64 * 32 * 2;
    unsigned short* wt2   = (unsigned short*)(ws + off); off += 9 * 64 * 64 * 2;
    float2* partials      = (float2*)(ws + off);         off += (size_t)3200 * 64 * sizeof(float2);
    float2* stats1        = (float2*)(ws + off);         off += 512 * sizeof(float2);
    float2* stats2        = (float2*)(ws + off);         off += 512 * sizeof(float2);

    dim3 cgrid(5, 80, BB);

    prep_hwc<<<dim3(5, HH, BB), 256, 0, stream>>>(x, x_hwc);
    wprep_kernel<<<144, 256, 0, stream>>>(w1, w2, wt1, wt2);

    // conv1: raw HWC in, raw HWC out + stats partials
    conv_mfma<32, 0, 0><<<cgrid, 256, 0, stream>>>(x_hwc, nullptr, wt1, b1,
                                                   h_hwc, partials, nullptr, nullptr);
    reduce_stats<<<BB, 256, 0, stream>>>(partials, stats1);
    // conv2 pass A: normalized input, stats partials only
    conv_mfma<64, 1, 1><<<cgrid, 256, 0, stream>>>(h_hwc, stats1, wt2, b2,
                                                   nullptr, partials, nullptr, nullptr);
    reduce_stats<<<BB, 256, 0, stream>>>(partials, stats2);
    // conv2 pass B: normalized input, final normalize+relu+transpose to NCHW fp32
    conv_mfma<64, 1, 2><<<cgrid, 256, 0, stream>>>(h_hwc, stats1, wt2, b2,
                                                   nullptr, nullptr, stats2, out);
}